// Round 1
// 78248.871 us; speedup vs baseline: 1.7847x; 1.7847x over previous
//
#include <hip/hip_runtime.h>

// CRSDBlock: 2-layer leaky reservoir RNN.
//   r_t = 0.9*r_{t-1} + 0.1*tanh(x_t@Wxr + h_{t-1}@Whr)
//   h_t = tanh(x_t@Wxh + h_{t-1}@Whh + r_t@Wrh)
// B=32, T=1024, D=R=1024, LAYERS=2.
//
// Round 4 (this session R1): restructure away from 4096 tiny dispatches.
//  - Xr = x@Wxr, Xh = x@Wxh hoisted out of the time loop (chunked batch GEMM).
//  - Persistent 64-block x 512-thread kernel runs CT=256 steps per launch with
//    an in-kernel grid barrier (monotonic counter + agent fences).
//  - Whr/Whh LDS-resident across steps; Wrh L2-resident; r state in registers.
//  - 8 waves/block: phase A 2-way K-split (Whr,Whh), phase B 4-way (Wrh),
//    LDS reduction.

#define D_DIM 1024
#define T_DIM 1024
#define B_DIM 32
#define XROW ((size_t)T_DIM * D_DIM)   // row stride of x / out per batch
#define KT_N 32                        // K tiles (1024/32)
#define NT_N 64                        // N tiles (1024/16)
#define CT 256                         // timesteps per persistent launch
#define NCHUNK (T_DIM / CT)
#define NB 64                          // blocks in recurrent grid (== NT_N)

typedef __attribute__((ext_vector_type(8))) short short8;
typedef __attribute__((ext_vector_type(4))) float f32x4;

__device__ __forceinline__ unsigned short f2bf(float f) {
    unsigned int u = __float_as_uint(f);
    unsigned int r = u + 0x7FFFu + ((u >> 16) & 1u);  // round-nearest-even
    return (unsigned short)(r >> 16);
}
__device__ __forceinline__ float bf2f(unsigned short h) {
    return __uint_as_float(((unsigned int)h) << 16);
}
struct BfPair { short hi, lo; };
__device__ __forceinline__ BfPair splitbf(float f) {
    BfPair p;
    unsigned short h = f2bf(f);
    p.hi = (short)h;
    p.lo = (short)f2bf(f - bf2f(h));
    return p;
}

__device__ __forceinline__ void ldfrag_split(const float* __restrict__ p,
                                             short8& hi, short8& lo) {
    f32x4 a = *(const f32x4*)p;
    f32x4 b = *(const f32x4*)(p + 4);
#pragma unroll
    for (int j = 0; j < 4; ++j) {
        BfPair s = splitbf(a[j]);
        hi[j] = s.hi; lo[j] = s.lo;
    }
#pragma unroll
    for (int j = 0; j < 4; ++j) {
        BfPair s = splitbf(b[j]);
        hi[4 + j] = s.hi; lo[4 + j] = s.lo;
    }
}

// 3-term split-bf16 MFMA accumulate: acc += (ah+al) @ (bh+bl), drop al*bl.
__device__ __forceinline__ f32x4 mfma3(short8 ah, short8 al, short8 bh,
                                       short8 bl, f32x4 acc) {
    acc = __builtin_amdgcn_mfma_f32_16x16x32_bf16(ah, bh, acc, 0, 0, 0);
    acc = __builtin_amdgcn_mfma_f32_16x16x32_bf16(al, bh, acc, 0, 0, 0);
    acc = __builtin_amdgcn_mfma_f32_16x16x32_bf16(ah, bl, acc, 0, 0, 0);
    return acc;
}

// Pack one [1024,1024] fp32 weight (K-major) into MFMA B-frag tiles, hi+lo:
// layout [kt][nt][lane] of 8 bf16 (16B); elem j = W[kt*32+quad*8+j][nt*16+col].
__global__ __launch_bounds__(256) void pack_w_kernel(
        const float* __restrict__ W, short* __restrict__ Ph,
        short* __restrict__ Pl) {
    int tid  = blockIdx.x * 256 + threadIdx.x;   // 0..131071
    int lane = tid & 63;
    int tile = tid >> 6;                         // 0..2047
    int nt = tile & 63;
    int kt = tile >> 6;
    int quad = lane >> 4, col = lane & 15;
    int k0 = kt * 32 + quad * 8;
    int n  = nt * 16 + col;
    short8 oh, ol;
#pragma unroll
    for (int j = 0; j < 8; ++j) {
        BfPair s = splitbf(W[(size_t)(k0 + j) * D_DIM + n]);
        oh[j] = s.hi; ol[j] = s.lo;
    }
    ((short8*)Ph)[tid] = oh;
    ((short8*)Pl)[tid] = ol;
}

// Batch GEMM for the hoisted x-projections over one chunk of timesteps:
// Xdst[ct][b][n] = sum_k src[b][t0+ct][k] * W[k][n], rows = 32*256 = 8192.
// grid 2048 x 256: wave = (mt 0..511, ntg 0..15), 4 N-tiles per wave.
__global__ __launch_bounds__(256) void gemm_x_kernel(
        const float* __restrict__ src, const short* __restrict__ Wh,
        const short* __restrict__ Wl, float* __restrict__ Xdst, int t0) {
    int tid  = blockIdx.x * 256 + threadIdx.x;
    int wave = tid >> 6;                 // 0..8191
    int lane = threadIdx.x & 63;
    int mt = wave >> 4, ntg = wave & 15;
    int quad = lane >> 4, col = lane & 15;
    int rr_a = mt * 16 + col;            // chunk-row for A load
    const float* arow =
        src + ((size_t)((rr_a >> 8) * 1024 + t0 + (rr_a & 255))) * 1024;
    const short8* W8h = (const short8*)Wh;
    const short8* W8l = (const short8*)Wl;
    f32x4 acc[4] = {{0.f,0.f,0.f,0.f},{0.f,0.f,0.f,0.f},
                    {0.f,0.f,0.f,0.f},{0.f,0.f,0.f,0.f}};
#pragma unroll 2
    for (int kt = 0; kt < KT_N; ++kt) {
        int k = kt * 32 + quad * 8;
        short8 ah, al;
        ldfrag_split(arow + k, ah, al);
#pragma unroll
        for (int a = 0; a < 4; ++a) {
            int wi = (kt * NT_N + ntg * 4 + a) * 64 + lane;
            acc[a] = mfma3(ah, al, W8h[wi], W8l[wi], acc[a]);
        }
    }
#pragma unroll
    for (int a = 0; a < 4; ++a) {
        int n = (ntg * 4 + a) * 16 + col;
#pragma unroll
        for (int i = 0; i < 4; ++i) {
            int rr = mt * 16 + quad * 4 + i;   // chunk-row for C store
            Xdst[(size_t)((rr & 255) * 32 + (rr >> 8)) * 1024 + n] = acc[a][i];
        }
    }
}

// Grid barrier: monotonic counter, no reset race. All 64 blocks co-resident
// (64 blocks x 1/CU on 256 CUs). Release: __threadfence flushes stores to
// coherence point (cross-XCD); acquire fence invalidates L1/L2 after wait.
__device__ __forceinline__ void grid_bar(unsigned* cnt) {
    __threadfence();
    __syncthreads();
    if (threadIdx.x == 0) {
        unsigned my = __hip_atomic_fetch_add(cnt, 1u, __ATOMIC_ACQ_REL,
                                             __HIP_MEMORY_SCOPE_AGENT);
        unsigned target = my - (my % NB) + NB;
        while (__hip_atomic_load(cnt, __ATOMIC_RELAXED,
                                 __HIP_MEMORY_SCOPE_AGENT) < target)
            __builtin_amdgcn_s_sleep(1);
        __builtin_amdgcn_fence(__ATOMIC_ACQUIRE, "agent");
    }
    __syncthreads();
}

// Persistent recurrent kernel: 64 blocks x 512 threads, CT steps per launch.
// Block g owns N-columns [16g,16g+16). Waves wv: mt=wv&1, kh=(wv>>1)&1,
// mm=wv>>2. Phase A: S1 = Xr + h@Whr (mm0) and P = Xh + h@Whh (mm1), 2-way
// K-split; r update in registers on wv0/1. Phase B: h = tanh(P + r@Wrh),
// 4-way K-split, reduced+written by wv4/5 (which hold P).
__global__ __launch_bounds__(512, 2) void recurrent_kernel(
        const short* __restrict__ Whr_h, const short* __restrict__ Whr_l,
        const short* __restrict__ Whh_h, const short* __restrict__ Whh_l,
        const short* __restrict__ Wrh_h, const short* __restrict__ Wrh_l,
        const float* __restrict__ Xr,    // [CT][32][1024]
        const float* __restrict__ Xh,    // [CT][32][1024]
        short* __restrict__ hbh, short* __restrict__ hbl,
        short* __restrict__ rbh, short* __restrict__ rbl,
        float* __restrict__ rf32, float* __restrict__ out,
        int t0, unsigned* __restrict__ bar) {
    extern __shared__ char smem[];
    short8* wlds = (short8*)smem;                 // [mat2][hl2][kt32][lane64]
    f32x4*  red  = (f32x4*)(smem + 131072);       // [wv8][lane64] = 8KB

    int g = blockIdx.x;                           // nt column tile
    int tix = threadIdx.x;
    int wv = tix >> 6, lane = tix & 63;
    int quad = lane >> 4, col = lane & 15;
    int mt = wv & 1, kh = (wv >> 1) & 1, mm = wv >> 2;
    int kq = wv >> 1;                             // phase-B K quarter
    int n0 = g * 16;

    // Stage Whr (mat0) + Whh (mat1), hi+lo, column slice g -> LDS (128 KiB).
    for (int i = tix; i < 2 * 2 * 32 * 64; i += 512) {
        int ln = i & 63, kt = (i >> 6) & 31, hl = (i >> 11) & 1, mat = i >> 12;
        const short* s = mat ? (hl ? Whh_l : Whh_h) : (hl ? Whr_l : Whr_h);
        wlds[i] = ((const short8*)s)[(kt * 64 + g) * 64 + ln];
    }
    __syncthreads();

    // Register-resident r (wv0: batches 0-15, wv1: 16-31 of this N slice).
    int rbase = (16 * mt + quad * 4) * 1024 + n0 + col;
    float rf[4];
    if (wv < 2) {
#pragma unroll
        for (int i = 0; i < 4; ++i) rf[i] = rf32[rbase + i * 1024];
    }

    int hoff = (16 * mt + col) * 1024;   // A rows for both phases
    int kh16 = kh * 16;
    const short8* Wr8h = (const short8*)Wrh_h;
    const short8* Wr8l = (const short8*)Wrh_l;

    for (int ct = 0; ct < CT; ++ct) {
        // Prefetch additive term (Xr for mm0, Xh for mm1) early.
        f32x4 addv = {0.f, 0.f, 0.f, 0.f};
        if (kh == 0) {
            const float* Xsrc = mm ? Xh : Xr;
#pragma unroll
            for (int i = 0; i < 4; ++i)
                addv[i] = Xsrc[(size_t)ct * 32768 +
                               (16 * mt + quad * 4 + i) * 1024 + n0 + col];
        }

        // ---- phase A: h @ (Whr|Whh), K-half kh ----
        f32x4 acc = {0.f, 0.f, 0.f, 0.f};
#pragma unroll 8
        for (int kt = kh16; kt < kh16 + 16; ++kt) {
            int k = kt * 32 + quad * 8;
            short8 ah = *(const short8*)(hbh + hoff + k);
            short8 al = *(const short8*)(hbl + hoff + k);
            short8 wh = wlds[((mm * 2 + 0) * 32 + kt) * 64 + lane];
            short8 wl = wlds[((mm * 2 + 1) * 32 + kt) * 64 + lane];
            acc = mfma3(ah, al, wh, wl, acc);
        }
        red[wv * 64 + lane] = acc;
        __syncthreads();
        f32x4 pacc = {0.f, 0.f, 0.f, 0.f};
        if (kh == 0) {
            f32x4 o = red[(wv ^ 2) * 64 + lane];   // partner K-half
            acc = acc + o;
            if (mm == 0) {
                // r update + publish r as hi/lo bf16
#pragma unroll
                for (int i = 0; i < 4; ++i) {
                    float rn = 0.9f * rf[i] + 0.1f * tanhf(addv[i] + acc[i]);
                    rf[i] = rn;
                    BfPair s = splitbf(rn);
                    rbh[rbase + i * 1024] = s.hi;
                    rbl[rbase + i * 1024] = s.lo;
                }
            } else {
                pacc = acc + addv;                 // P = Xh + h@Whh
            }
        }
        grid_bar(bar);                             // r visible to all blocks

        // ---- phase B: r @ Wrh, K-quarter kq ----
        f32x4 accB = {0.f, 0.f, 0.f, 0.f};
        int kb = kq * 8;
#pragma unroll
        for (int kt = kb; kt < kb + 8; ++kt) {
            int k = kt * 32 + quad * 8;
            short8 ah = *(const short8*)(rbh + hoff + k);
            short8 al = *(const short8*)(rbl + hoff + k);
            int wi = (kt * 64 + g) * 64 + lane;
            accB = mfma3(ah, al, Wr8h[wi], Wr8l[wi], accB);
        }
        red[wv * 64 + lane] = accB;
        __syncthreads();
        if (mm == 1 && kh == 0) {                  // wv4 (mt0), wv5 (mt1)
            f32x4 s0 = red[(mt + 0) * 64 + lane];
            f32x4 s1 = red[(mt + 2) * 64 + lane];
            f32x4 s2 = red[(mt + 4) * 64 + lane];
            f32x4 s3 = red[(mt + 6) * 64 + lane];
#pragma unroll
            for (int i = 0; i < 4; ++i) {
                float hv = tanhf(pacc[i] + s0[i] + s1[i] + s2[i] + s3[i]);
                int b = 16 * mt + quad * 4 + i;
                int n = n0 + col;
                out[(size_t)b * XROW + (size_t)(t0 + ct) * 1024 + n] = hv;
                BfPair sp = splitbf(hv);
                hbh[b * 1024 + n] = sp.hi;
                hbl[b * 1024 + n] = sp.lo;
            }
        }
        grid_bar(bar);                             // h visible to all blocks
    }

    if (wv < 2) {
#pragma unroll
        for (int i = 0; i < 4; ++i) rf32[rbase + i * 1024] = rf[i];
    }
}

extern "C" void kernel_launch(void* const* d_in, const int* in_sizes, int n_in,
                              void* d_out, int out_size, void* d_ws,
                              size_t ws_size, hipStream_t stream) {
    const float* x_seq = (const float*)d_in[0];
    // d_in[1..5]: W_xh, W_hh, W_rh, W_xr, W_hr, each [2,1024,1024] fp32
    float* out = (float*)d_out;

    const size_t WSZ = (size_t)D_DIM * D_DIM;

    auto pwHi = [&](int l, int wi) {
        return (short*)d_ws + ((size_t)(l * 5 + wi)) * 2 * WSZ;
    };
    auto pwLo = [&](int l, int wi) {
        return (short*)d_ws + ((size_t)(l * 5 + wi)) * 2 * WSZ + WSZ;
    };
    char* sp = (char*)d_ws + 20 * WSZ * sizeof(short);   // after 40 MB packs
    float* Xr = (float*)sp; sp += (size_t)CT * B_DIM * D_DIM * sizeof(float);
    float* Xh = (float*)sp; sp += (size_t)CT * B_DIM * D_DIM * sizeof(float);
    const size_t SB = (size_t)B_DIM * D_DIM;
    short* hbh = (short*)sp; sp += SB * sizeof(short);
    short* hbl = (short*)sp; sp += SB * sizeof(short);
    short* rbh = (short*)sp; sp += SB * sizeof(short);
    short* rbl = (short*)sp; sp += SB * sizeof(short);
    float* rf32 = (float*)sp; sp += SB * sizeof(float);
    unsigned* bar = (unsigned*)sp; sp += 256;

    const size_t SMEM = 131072 + 8192;   // weights + reduce = 136 KiB
    static bool attr_set = false;
    if (!attr_set) {
        (void)hipFuncSetAttribute((const void*)recurrent_kernel,
                                  hipFuncAttributeMaxDynamicSharedMemorySize,
                                  (int)SMEM);
        attr_set = true;
    }

    // Pack all 10 weight matrices. Input order: 0=W_xh 1=W_hh 2=W_rh 3=W_xr
    // 4=W_hr.
    for (int l = 0; l < 2; ++l)
        for (int wi = 0; wi < 5; ++wi)
            pack_w_kernel<<<512, 256, 0, stream>>>(
                (const float*)d_in[1 + wi] + (size_t)l * WSZ,
                pwHi(l, wi), pwLo(l, wi));

    for (int l = 0; l < 2; ++l) {
        const float* src = (l == 0) ? x_seq : out;   // layer-2 reads L1 output
        (void)hipMemsetAsync(hbh, 0, SB * sizeof(short), stream);
        (void)hipMemsetAsync(hbl, 0, SB * sizeof(short), stream);
        (void)hipMemsetAsync(rf32, 0, SB * sizeof(float), stream);
        (void)hipMemsetAsync(bar, 0, 256, stream);
        for (int c = 0; c < NCHUNK; ++c) {
            int t0 = c * CT;
            // Hoisted projections for this chunk (read rows not yet
            // overwritten by this layer's recurrent output).
            gemm_x_kernel<<<2048, 256, 0, stream>>>(src, pwHi(l, 3),
                                                    pwLo(l, 3), Xr, t0);
            gemm_x_kernel<<<2048, 256, 0, stream>>>(src, pwHi(l, 0),
                                                    pwLo(l, 0), Xh, t0);
            recurrent_kernel<<<NB, 512, SMEM, stream>>>(
                pwHi(l, 4), pwLo(l, 4),   // Whr
                pwHi(l, 1), pwLo(l, 1),   // Whh
                pwHi(l, 2), pwLo(l, 2),   // Wrh
                Xr, Xh, hbh, hbl, rbh, rbl, rf32, out, t0, bar);
        }
    }
}

// Round 2
// 58287.482 us; speedup vs baseline: 2.3959x; 1.3425x over previous
//
#include <hip/hip_runtime.h>

// CRSDBlock: 2-layer leaky reservoir RNN.
//   r_t = 0.9*r_{t-1} + 0.1*tanh(x_t@Wxr + h_{t-1}@Whr)
//   h_t = tanh(x_t@Wxh + h_{t-1}@Whh + r_t@Wrh)
// B=32, T=1024, D=R=1024, LAYERS=2.
//
// R2 (this session): kill the fence cost in the grid barrier.
//  - Cross-block state (h, r) packed as u32 (bf16hi<<16|bf16lo) and moved
//    via agent-scope relaxed atomics (sc0 sc1 -> LLC, bypasses non-coherent
//    per-XCD L2). No __threadfence / acquire fence -> no buffer_wbl2 /
//    buffer_inv -> Wrh + Xr/Xh stay L2-resident across all 256 steps.
//  - 64-flag arrival barrier: lane i polls flag i; __syncthreads' vmcnt(0)
//    drain is the release; workgroup acquire fence pins compiler ordering.

#define D_DIM 1024
#define T_DIM 1024
#define B_DIM 32
#define XROW ((size_t)T_DIM * D_DIM)   // row stride of x / out per batch
#define KT_N 32                        // K tiles (1024/32)
#define NT_N 64                        // N tiles (1024/16)
#define CT 256                         // timesteps per persistent launch
#define NCHUNK (T_DIM / CT)
#define NB 64                          // blocks in recurrent grid (== NT_N)

typedef __attribute__((ext_vector_type(8))) short short8;
typedef __attribute__((ext_vector_type(4))) float f32x4;
typedef unsigned int u32;
typedef unsigned long long u64;

__device__ __forceinline__ unsigned short f2bf(float f) {
    unsigned int u = __float_as_uint(f);
    unsigned int r = u + 0x7FFFu + ((u >> 16) & 1u);  // round-nearest-even
    return (unsigned short)(r >> 16);
}
__device__ __forceinline__ float bf2f(unsigned short h) {
    return __uint_as_float(((unsigned int)h) << 16);
}
struct BfPair { short hi, lo; };
__device__ __forceinline__ BfPair splitbf(float f) {
    BfPair p;
    unsigned short h = f2bf(f);
    p.hi = (short)h;
    p.lo = (short)f2bf(f - bf2f(h));
    return p;
}
// Pack split-bf16 into one u32: hi in bits 31:16, lo in 15:0.
__device__ __forceinline__ u32 pkbf(float f) {
    BfPair s = splitbf(f);
    return ((u32)(unsigned short)s.hi << 16) | (u32)(unsigned short)s.lo;
}

__device__ __forceinline__ void ldfrag_split(const float* __restrict__ p,
                                             short8& hi, short8& lo) {
    f32x4 a = *(const f32x4*)p;
    f32x4 b = *(const f32x4*)(p + 4);
#pragma unroll
    for (int j = 0; j < 4; ++j) {
        BfPair s = splitbf(a[j]);
        hi[j] = s.hi; lo[j] = s.lo;
    }
#pragma unroll
    for (int j = 0; j < 4; ++j) {
        BfPair s = splitbf(b[j]);
        hi[4 + j] = s.hi; lo[4 + j] = s.lo;
    }
}

// Load 8 packed u32 (hi|lo) from LLC via agent-scope relaxed atomics and
// unpack into hi/lo bf16 MFMA A-fragments. p must be 8B-aligned.
__device__ __forceinline__ void ld_pk8(const u32* __restrict__ p,
                                       short8& hi, short8& lo) {
    u64 d[4];
#pragma unroll
    for (int j = 0; j < 4; ++j)
        d[j] = __hip_atomic_load((const u64*)p + j, __ATOMIC_RELAXED,
                                 __HIP_MEMORY_SCOPE_AGENT);
#pragma unroll
    for (int j = 0; j < 4; ++j) {
        u32 w0 = (u32)d[j], w1 = (u32)(d[j] >> 32);
        hi[2 * j]     = (short)(w0 >> 16);
        lo[2 * j]     = (short)(w0 & 0xffffu);
        hi[2 * j + 1] = (short)(w1 >> 16);
        lo[2 * j + 1] = (short)(w1 & 0xffffu);
    }
}

// 3-term split-bf16 MFMA accumulate: acc += (ah+al) @ (bh+bl), drop al*bl.
__device__ __forceinline__ f32x4 mfma3(short8 ah, short8 al, short8 bh,
                                       short8 bl, f32x4 acc) {
    acc = __builtin_amdgcn_mfma_f32_16x16x32_bf16(ah, bh, acc, 0, 0, 0);
    acc = __builtin_amdgcn_mfma_f32_16x16x32_bf16(al, bh, acc, 0, 0, 0);
    acc = __builtin_amdgcn_mfma_f32_16x16x32_bf16(ah, bl, acc, 0, 0, 0);
    return acc;
}

// Pack one [1024,1024] fp32 weight (K-major) into MFMA B-frag tiles, hi+lo:
// layout [kt][nt][lane] of 8 bf16 (16B); elem j = W[kt*32+quad*8+j][nt*16+col].
__global__ __launch_bounds__(256) void pack_w_kernel(
        const float* __restrict__ W, short* __restrict__ Ph,
        short* __restrict__ Pl) {
    int tid  = blockIdx.x * 256 + threadIdx.x;   // 0..131071
    int lane = tid & 63;
    int tile = tid >> 6;                         // 0..2047
    int nt = tile & 63;
    int kt = tile >> 6;
    int quad = lane >> 4, col = lane & 15;
    int k0 = kt * 32 + quad * 8;
    int n  = nt * 16 + col;
    short8 oh, ol;
#pragma unroll
    for (int j = 0; j < 8; ++j) {
        BfPair s = splitbf(W[(size_t)(k0 + j) * D_DIM + n]);
        oh[j] = s.hi; ol[j] = s.lo;
    }
    ((short8*)Ph)[tid] = oh;
    ((short8*)Pl)[tid] = ol;
}

// Batch GEMM for the hoisted x-projections over one chunk of timesteps:
// Xdst[ct][b][n] = sum_k src[b][t0+ct][k] * W[k][n], rows = 32*256 = 8192.
// grid 2048 x 256: wave = (mt 0..511, ntg 0..15), 4 N-tiles per wave.
__global__ __launch_bounds__(256) void gemm_x_kernel(
        const float* __restrict__ src, const short* __restrict__ Wh,
        const short* __restrict__ Wl, float* __restrict__ Xdst, int t0) {
    int tid  = blockIdx.x * 256 + threadIdx.x;
    int wave = tid >> 6;                 // 0..8191
    int lane = threadIdx.x & 63;
    int mt = wave >> 4, ntg = wave & 15;
    int quad = lane >> 4, col = lane & 15;
    int rr_a = mt * 16 + col;            // chunk-row for A load
    const float* arow =
        src + ((size_t)((rr_a >> 8) * 1024 + t0 + (rr_a & 255))) * 1024;
    const short8* W8h = (const short8*)Wh;
    const short8* W8l = (const short8*)Wl;
    f32x4 acc[4] = {{0.f,0.f,0.f,0.f},{0.f,0.f,0.f,0.f},
                    {0.f,0.f,0.f,0.f},{0.f,0.f,0.f,0.f}};
#pragma unroll 2
    for (int kt = 0; kt < KT_N; ++kt) {
        int k = kt * 32 + quad * 8;
        short8 ah, al;
        ldfrag_split(arow + k, ah, al);
#pragma unroll
        for (int a = 0; a < 4; ++a) {
            int wi = (kt * NT_N + ntg * 4 + a) * 64 + lane;
            acc[a] = mfma3(ah, al, W8h[wi], W8l[wi], acc[a]);
        }
    }
#pragma unroll
    for (int a = 0; a < 4; ++a) {
        int n = (ntg * 4 + a) * 16 + col;
#pragma unroll
        for (int i = 0; i < 4; ++i) {
            int rr = mt * 16 + quad * 4 + i;   // chunk-row for C store
            Xdst[(size_t)((rr & 255) * 32 + (rr >> 8)) * 1024 + n] = acc[a][i];
        }
    }
}

// Fence-free grid barrier. Preconditions: all cross-block data stores are
// agent-scope atomics (write-through to LLC), and callers reach this via
// __syncthreads (vmcnt(0) drain = release). Lane i of wave 0 polls flag i.
// tgt is monotonically increasing across the layer -> no reset race.
__device__ __forceinline__ void grid_bar2(u32* __restrict__ flags, u32 tgt) {
    __syncthreads();   // drains all waves' stores (vmcnt 0) + joins block
    if (threadIdx.x < NB) {
        if (threadIdx.x == 0)
            __hip_atomic_store(&flags[blockIdx.x], tgt, __ATOMIC_RELAXED,
                               __HIP_MEMORY_SCOPE_AGENT);
        while (__hip_atomic_load(&flags[threadIdx.x], __ATOMIC_RELAXED,
                                 __HIP_MEMORY_SCOPE_AGENT) < tgt) {}
    }
    __builtin_amdgcn_fence(__ATOMIC_ACQUIRE, "workgroup");  // order, no inv
    __syncthreads();
}

// Persistent recurrent kernel: 64 blocks x 512 threads, CT steps per launch.
// Block g owns N-columns [16g,16g+16). Waves wv: mt=wv&1, kh=(wv>>1)&1,
// mm=wv>>2. Phase A: S1 = Xr + h@Whr (mm0) and P = Xh + h@Whh (mm1), 2-way
// K-split; r update in registers on wv0/1. Phase B: h = tanh(P + r@Wrh),
// 4-way K-split, reduced+written by wv4/5 (which hold P).
__global__ __launch_bounds__(512, 2) void recurrent_kernel(
        const short* __restrict__ Whr_h, const short* __restrict__ Whr_l,
        const short* __restrict__ Whh_h, const short* __restrict__ Whh_l,
        const short* __restrict__ Wrh_h, const short* __restrict__ Wrh_l,
        const float* __restrict__ Xr,    // [CT][32][1024]
        const float* __restrict__ Xh,    // [CT][32][1024]
        u32* __restrict__ hpk,           // h state, packed hi|lo [32][1024]
        u32* __restrict__ rpk,           // r state, packed hi|lo [32][1024]
        float* __restrict__ rf32, float* __restrict__ out,
        int t0, u32* __restrict__ flags) {
    extern __shared__ char smem[];
    short8* wlds = (short8*)smem;                 // [mat2][hl2][kt32][lane64]
    f32x4*  red  = (f32x4*)(smem + 131072);       // [wv8][lane64] = 8KB

    int g = blockIdx.x;                           // nt column tile
    int tix = threadIdx.x;
    int wv = tix >> 6, lane = tix & 63;
    int quad = lane >> 4, col = lane & 15;
    int mt = wv & 1, kh = (wv >> 1) & 1, mm = wv >> 2;
    int kq = wv >> 1;                             // phase-B K quarter
    int n0 = g * 16;

    // Stage Whr (mat0) + Whh (mat1), hi+lo, column slice g -> LDS (128 KiB).
    for (int i = tix; i < 2 * 2 * 32 * 64; i += 512) {
        int ln = i & 63, kt = (i >> 6) & 31, hl = (i >> 11) & 1, mat = i >> 12;
        const short* s = mat ? (hl ? Whh_l : Whh_h) : (hl ? Whr_l : Whr_h);
        wlds[i] = ((const short8*)s)[(kt * 64 + g) * 64 + ln];
    }
    __syncthreads();

    // Register-resident r (wv0: batches 0-15, wv1: 16-31 of this N slice).
    int rbase = (16 * mt + quad * 4) * 1024 + n0 + col;
    float rf[4];
    if (wv < 2) {
#pragma unroll
        for (int i = 0; i < 4; ++i) rf[i] = rf32[rbase + i * 1024];
    }

    int hoff = (16 * mt + col) * 1024;   // A rows for both phases
    int kh16 = kh * 16;
    const short8* Wr8h = (const short8*)Wrh_h;
    const short8* Wr8l = (const short8*)Wrh_l;

    for (int ct = 0; ct < CT; ++ct) {
        u32 tgt = (u32)(t0 + ct) * 2;

        // Prefetch additive term (Xr for mm0, Xh for mm1) early.
        f32x4 addv = {0.f, 0.f, 0.f, 0.f};
        if (kh == 0) {
            const float* Xsrc = mm ? Xh : Xr;
#pragma unroll
            for (int i = 0; i < 4; ++i)
                addv[i] = Xsrc[(size_t)ct * 32768 +
                               (16 * mt + quad * 4 + i) * 1024 + n0 + col];
        }

        // ---- phase A: h @ (Whr|Whh), K-half kh ----
        f32x4 acc = {0.f, 0.f, 0.f, 0.f};
#pragma unroll 8
        for (int kt = kh16; kt < kh16 + 16; ++kt) {
            int k = kt * 32 + quad * 8;
            short8 ah, al;
            ld_pk8(hpk + hoff + k, ah, al);
            short8 wh = wlds[((mm * 2 + 0) * 32 + kt) * 64 + lane];
            short8 wl = wlds[((mm * 2 + 1) * 32 + kt) * 64 + lane];
            acc = mfma3(ah, al, wh, wl, acc);
        }
        red[wv * 64 + lane] = acc;
        __syncthreads();
        f32x4 pacc = {0.f, 0.f, 0.f, 0.f};
        if (kh == 0) {
            f32x4 o = red[(wv ^ 2) * 64 + lane];   // partner K-half
            acc = acc + o;
            if (mm == 0) {
                // r update + publish r packed split-bf16 to LLC
#pragma unroll
                for (int i = 0; i < 4; ++i) {
                    float rn = 0.9f * rf[i] + 0.1f * tanhf(addv[i] + acc[i]);
                    rf[i] = rn;
                    __hip_atomic_store(&rpk[rbase + i * 1024], pkbf(rn),
                                       __ATOMIC_RELAXED,
                                       __HIP_MEMORY_SCOPE_AGENT);
                }
            } else {
                pacc = acc + addv;                 // P = Xh + h@Whh
            }
        }
        grid_bar2(flags, tgt + 1);                 // r visible to all blocks

        // ---- phase B: r @ Wrh, K-quarter kq ----
        f32x4 accB = {0.f, 0.f, 0.f, 0.f};
        int kb = kq * 8;
#pragma unroll
        for (int kt = kb; kt < kb + 8; ++kt) {
            int k = kt * 32 + quad * 8;
            short8 ah, al;
            ld_pk8(rpk + hoff + k, ah, al);
            int wi = (kt * 64 + g) * 64 + lane;
            accB = mfma3(ah, al, Wr8h[wi], Wr8l[wi], accB);
        }
        red[wv * 64 + lane] = accB;
        __syncthreads();
        if (mm == 1 && kh == 0) {                  // wv4 (mt0), wv5 (mt1)
            f32x4 s0 = red[(mt + 0) * 64 + lane];
            f32x4 s1 = red[(mt + 2) * 64 + lane];
            f32x4 s2 = red[(mt + 4) * 64 + lane];
            f32x4 s3 = red[(mt + 6) * 64 + lane];
#pragma unroll
            for (int i = 0; i < 4; ++i) {
                float hv = tanhf(pacc[i] + s0[i] + s1[i] + s2[i] + s3[i]);
                int b = 16 * mt + quad * 4 + i;
                int n = n0 + col;
                out[(size_t)b * XROW + (size_t)(t0 + ct) * 1024 + n] = hv;
                __hip_atomic_store(&hpk[b * 1024 + n], pkbf(hv),
                                   __ATOMIC_RELAXED,
                                   __HIP_MEMORY_SCOPE_AGENT);
            }
        }
        grid_bar2(flags, tgt + 2);                 // h visible to all blocks
    }

    if (wv < 2) {
#pragma unroll
        for (int i = 0; i < 4; ++i) rf32[rbase + i * 1024] = rf[i];
    }
}

extern "C" void kernel_launch(void* const* d_in, const int* in_sizes, int n_in,
                              void* d_out, int out_size, void* d_ws,
                              size_t ws_size, hipStream_t stream) {
    const float* x_seq = (const float*)d_in[0];
    // d_in[1..5]: W_xh, W_hh, W_rh, W_xr, W_hr, each [2,1024,1024] fp32
    float* out = (float*)d_out;

    const size_t WSZ = (size_t)D_DIM * D_DIM;

    auto pwHi = [&](int l, int wi) {
        return (short*)d_ws + ((size_t)(l * 5 + wi)) * 2 * WSZ;
    };
    auto pwLo = [&](int l, int wi) {
        return (short*)d_ws + ((size_t)(l * 5 + wi)) * 2 * WSZ + WSZ;
    };
    char* sp = (char*)d_ws + 20 * WSZ * sizeof(short);   // after 40 MB packs
    float* Xr = (float*)sp; sp += (size_t)CT * B_DIM * D_DIM * sizeof(float);
    float* Xh = (float*)sp; sp += (size_t)CT * B_DIM * D_DIM * sizeof(float);
    const size_t SB = (size_t)B_DIM * D_DIM;
    u32* hpk = (u32*)sp; sp += SB * sizeof(u32);
    u32* rpk = (u32*)sp; sp += SB * sizeof(u32);
    float* rf32 = (float*)sp; sp += SB * sizeof(float);
    u32* flags = (u32*)sp; sp += 256;

    const size_t SMEM = 131072 + 8192;   // weights + reduce = 136 KiB
    static bool attr_set = false;
    if (!attr_set) {
        (void)hipFuncSetAttribute((const void*)recurrent_kernel,
                                  hipFuncAttributeMaxDynamicSharedMemorySize,
                                  (int)SMEM);
        attr_set = true;
    }

    // Pack all 10 weight matrices. Input order: 0=W_xh 1=W_hh 2=W_rh 3=W_xr
    // 4=W_hr.
    for (int l = 0; l < 2; ++l)
        for (int wi = 0; wi < 5; ++wi)
            pack_w_kernel<<<512, 256, 0, stream>>>(
                (const float*)d_in[1 + wi] + (size_t)l * WSZ,
                pwHi(l, wi), pwLo(l, wi));

    for (int l = 0; l < 2; ++l) {
        const float* src = (l == 0) ? x_seq : out;   // layer-2 reads L1 output
        (void)hipMemsetAsync(hpk, 0, SB * sizeof(u32), stream);
        (void)hipMemsetAsync(rf32, 0, SB * sizeof(float), stream);
        (void)hipMemsetAsync(flags, 0, 256, stream);
        for (int c = 0; c < NCHUNK; ++c) {
            int t0 = c * CT;
            // Hoisted projections for this chunk.
            gemm_x_kernel<<<2048, 256, 0, stream>>>(src, pwHi(l, 3),
                                                    pwLo(l, 3), Xr, t0);
            gemm_x_kernel<<<2048, 256, 0, stream>>>(src, pwHi(l, 0),
                                                    pwLo(l, 0), Xh, t0);
            recurrent_kernel<<<NB, 512, SMEM, stream>>>(
                pwHi(l, 4), pwLo(l, 4),   // Whr
                pwHi(l, 1), pwLo(l, 1),   // Whh
                pwHi(l, 2), pwLo(l, 2),   // Wrh
                Xr, Xh, hpk, rpk, rf32, out, t0, flags);
        }
    }
}